// Round 1
// baseline (161.510 us; speedup 1.0000x reference)
//
#include <hip/hip_runtime.h>
#include <hip/hip_bf16.h>

#define NN 100000   // nodes
#define H  256      // feature dim
#define NE 300000   // edges
#define KOUT 512    // y row length (u | v)

typedef __attribute__((ext_vector_type(8))) short short8;
typedef __attribute__((ext_vector_type(8))) unsigned short ushort8v;
typedef __attribute__((ext_vector_type(4))) float f32x4;

__device__ __forceinline__ unsigned short f2bf(float f) {
    unsigned int u = __float_as_uint(f);
    u += 0x7FFFu + ((u >> 16) & 1u);   // RNE
    return (unsigned short)(u >> 16);
}
__device__ __forceinline__ float bf2f(unsigned short h) {
    return __uint_as_float(((unsigned int)h) << 16);
}
// byte offset into a [rows][64] bf16 LDS tile (128B rows), XOR-swizzled
__device__ __forceinline__ int swz(int row, int coloff) {
    return row * 128 + (coloff ^ ((row & 7) << 4));
}

// ---------------- Phase 1: y[100000][512] = x[100000][256] @ Wcat[256][512] (bf16 MFMA)
// Wcat[k][j] = (j<256) ? W1[k][j] : W1[k+256][j-256]
__global__ __launch_bounds__(256) void gemm_phase1(const float* __restrict__ x,
                                                   const float* __restrict__ W1,
                                                   unsigned short* __restrict__ y) {
    __shared__ unsigned short Al[128 * 64];  // [m][k] swizzled
    __shared__ unsigned short Bl[128 * 64];  // [n][k] (B transposed) swizzled

    const int tid = threadIdx.x;
    const int bid = blockIdx.x;
    const int mt = bid >> 2;          // 4 N-tiles of 128 over N=512
    const int nt = bid & 3;
    const int m0 = mt * 128, n0 = nt * 128;
    const int lane = tid & 63, wid = tid >> 6;
    const int wm = (wid >> 1) * 64, wn = (wid & 1) * 64;
    const int lr = lane & 15, lk = lane >> 4;

    f32x4 acc[4][4] = {};

    for (int ks = 0; ks < 4; ++ks) {   // K=256, BK=64
        const int k0 = ks * 64;
        if (ks) __syncthreads();
        // ---- stage A: 128 rows x 64 k, fp32 -> bf16, swizzled
        #pragma unroll
        for (int pass = 0; pass < 2; ++pass) {
            int f = pass * 4096 + tid * 16;
            int row = f >> 6, col = f & 63;
            int node = m0 + row;
            node = node < NN ? node : NN - 1;  // clamp; rows >= NN never stored
            const float* src = x + (size_t)node * H + k0 + col;
            float4 v0 = *(const float4*)(src + 0);
            float4 v1 = *(const float4*)(src + 4);
            float4 v2 = *(const float4*)(src + 8);
            float4 v3 = *(const float4*)(src + 12);
            ushort8v p0, p1;
            p0[0]=f2bf(v0.x); p0[1]=f2bf(v0.y); p0[2]=f2bf(v0.z); p0[3]=f2bf(v0.w);
            p0[4]=f2bf(v1.x); p0[5]=f2bf(v1.y); p0[6]=f2bf(v1.z); p0[7]=f2bf(v1.w);
            p1[0]=f2bf(v2.x); p1[1]=f2bf(v2.y); p1[2]=f2bf(v2.z); p1[3]=f2bf(v2.w);
            p1[4]=f2bf(v3.x); p1[5]=f2bf(v3.y); p1[6]=f2bf(v3.z); p1[7]=f2bf(v3.w);
            *(ushort8v*)((char*)Al + swz(row, col * 2))      = p0;
            *(ushort8v*)((char*)Al + swz(row, col * 2 + 16)) = p1;
        }
        // ---- stage B transposed: Bl[n][k], n in [0,128), k in [0,64)
        {
            int j  = tid & 127;       // column within tile
            int kh = tid >> 7;        // 0..1, each covers 32 k's
            int rowbase = (n0 >= 256) ? 256 : 0;
            const float* wp = W1 + (size_t)(k0 + kh * 32 + rowbase) * 256 + (n0 & 255) + j;
            #pragma unroll
            for (int q = 0; q < 4; ++q) {
                ushort8v p;
                #pragma unroll
                for (int i = 0; i < 8; ++i) p[i] = f2bf(wp[(q * 8 + i) * 256]);
                *(ushort8v*)((char*)Bl + swz(j, (kh * 32 + q * 8) * 2)) = p;
            }
        }
        __syncthreads();
        // ---- MFMA over BK=64 (two K=32 steps)
        #pragma unroll
        for (int kk = 0; kk < 64; kk += 32) {
            short8 a[4], b[4];
            const int coloff = kk * 2 + lk * 16;
            #pragma unroll
            for (int mi = 0; mi < 4; ++mi)
                a[mi] = *(const short8*)((const char*)Al + swz(wm + mi * 16 + lr, coloff));
            #pragma unroll
            for (int ni = 0; ni < 4; ++ni)
                b[ni] = *(const short8*)((const char*)Bl + swz(wn + ni * 16 + lr, coloff));
            #pragma unroll
            for (int mi = 0; mi < 4; ++mi)
                #pragma unroll
                for (int ni = 0; ni < 4; ++ni)
                    acc[mi][ni] = __builtin_amdgcn_mfma_f32_16x16x32_bf16(a[mi], b[ni], acc[mi][ni], 0, 0, 0);
        }
    }
    // ---- epilogue: D row=(lane>>4)*4+r, col=lane&15 (verified layout)
    #pragma unroll
    for (int mi = 0; mi < 4; ++mi) {
        #pragma unroll
        for (int ni = 0; ni < 4; ++ni) {
            const int col = n0 + wn + ni * 16 + lr;
            #pragma unroll
            for (int r = 0; r < 4; ++r) {
                const int rowg = m0 + wm + mi * 16 + lk * 4 + r;
                if (rowg < NN) y[(size_t)rowg * KOUT + col] = f2bf(acc[mi][ni][r]);
            }
        }
    }
}

// ---------------- Phase 2: per-edge relu-combine + dot(W2). One wave per edge.
__global__ __launch_bounds__(256) void edge_phase2(const unsigned short* __restrict__ y,
                                                   const int* __restrict__ ei,
                                                   const float* __restrict__ b1,
                                                   const float* __restrict__ W2,
                                                   const float* __restrict__ b2,
                                                   float* __restrict__ out) {
    const int lane = threadIdx.x & 63;
    const int gw = (blockIdx.x * blockDim.x + threadIdx.x) >> 6;
    const int nw = (gridDim.x * blockDim.x) >> 6;
    const int j = lane * 4;
    const float4 bv = *(const float4*)(b1 + j);
    const float4 wv = *(const float4*)(W2 + j);
    const float bb = b2[0];
    for (int e = gw; e < NE; e += nw) {
        int s = ei[e], d = ei[NE + e];
        s = min(max(s, 0), NN - 1);
        d = min(max(d, 0), NN - 1);
        ushort4 us = *(const ushort4*)(y + (size_t)s * KOUT + j);
        ushort4 ud = *(const ushort4*)(y + (size_t)d * KOUT + 256 + j);
        float h0 = fmaxf(bf2f(us.x) + bf2f(ud.x) + bv.x, 0.f);
        float h1 = fmaxf(bf2f(us.y) + bf2f(ud.y) + bv.y, 0.f);
        float h2 = fmaxf(bf2f(us.z) + bf2f(ud.z) + bv.z, 0.f);
        float h3 = fmaxf(bf2f(us.w) + bf2f(ud.w) + bv.w, 0.f);
        float acc = h0 * wv.x + h1 * wv.y + h2 * wv.z + h3 * wv.w;
        #pragma unroll
        for (int off = 32; off > 0; off >>= 1) acc += __shfl_xor(acc, off, 64);
        if (lane == 0) out[e] = acc + bb;
    }
}

// ---------------- Fallback (ws too small): fused wave-per-edge, fp32. Slow but correct.
__global__ __launch_bounds__(256) void fused_fallback(const float* __restrict__ x,
                                                      const int* __restrict__ ei,
                                                      const float* __restrict__ W1,
                                                      const float* __restrict__ b1,
                                                      const float* __restrict__ W2,
                                                      const float* __restrict__ b2,
                                                      float* __restrict__ out) {
    __shared__ float xsh[4][512];
    const int lane = threadIdx.x & 63;
    const int wl = threadIdx.x >> 6;
    const int gw = (blockIdx.x * blockDim.x + threadIdx.x) >> 6;
    const int nw = (gridDim.x * blockDim.x) >> 6;
    const int j = lane * 4;
    const float4 bv = *(const float4*)(b1 + j);
    const float4 wv = *(const float4*)(W2 + j);
    const float bb = b2[0];
    for (int e = gw; e < NE; e += nw) {
        int s = ei[e], d = ei[NE + e];
        s = min(max(s, 0), NN - 1);
        d = min(max(d, 0), NN - 1);
        __threadfence_block();   // order prior reads before overwrite
        #pragma unroll
        for (int i = 0; i < 4; ++i) {
            xsh[wl][i * 64 + lane]       = x[(size_t)s * H + i * 64 + lane];
            xsh[wl][256 + i * 64 + lane] = x[(size_t)d * H + i * 64 + lane];
        }
        __threadfence_block();   // order writes before reads (wave-private tile)
        float h0 = bv.x, h1 = bv.y, h2 = bv.z, h3 = bv.w;
        for (int k = 0; k < 256; ++k) {
            float xa = xsh[wl][k], xb = xsh[wl][256 + k];
            float4 wa = *(const float4*)(W1 + (size_t)k * 256 + j);
            float4 wb = *(const float4*)(W1 + (size_t)(k + 256) * 256 + j);
            h0 += xa * wa.x + xb * wb.x;
            h1 += xa * wa.y + xb * wb.y;
            h2 += xa * wa.z + xb * wb.z;
            h3 += xa * wa.w + xb * wb.w;
        }
        float acc = fmaxf(h0, 0.f) * wv.x + fmaxf(h1, 0.f) * wv.y +
                    fmaxf(h2, 0.f) * wv.z + fmaxf(h3, 0.f) * wv.w;
        #pragma unroll
        for (int off = 32; off > 0; off >>= 1) acc += __shfl_xor(acc, off, 64);
        if (lane == 0) out[e] = acc + bb;
    }
}

extern "C" void kernel_launch(void* const* d_in, const int* in_sizes, int n_in,
                              void* d_out, int out_size, void* d_ws, size_t ws_size,
                              hipStream_t stream) {
    const float* x  = (const float*)d_in[0];
    const int*   ei = (const int*)d_in[1];
    const float* W1 = (const float*)d_in[2];
    const float* b1 = (const float*)d_in[3];
    const float* W2 = (const float*)d_in[4];
    const float* b2 = (const float*)d_in[5];
    float* out = (float*)d_out;

    const size_t need = (size_t)NN * KOUT * sizeof(unsigned short);  // 102.4 MB
    if (ws_size >= need) {
        unsigned short* y = (unsigned short*)d_ws;
        const int mtiles = (NN + 127) / 128;  // 782
        gemm_phase1<<<dim3(mtiles * 4), dim3(256), 0, stream>>>(x, W1, y);
        edge_phase2<<<dim3(2048), dim3(256), 0, stream>>>(y, ei, b1, W2, b2, out);
    } else {
        fused_fallback<<<dim3(2048), dim3(256), 0, stream>>>(x, ei, W1, b1, W2, b2, out);
    }
}

// Round 2
// 117.470 us; speedup vs baseline: 1.3749x; 1.3749x over previous
//
#include <hip/hip_runtime.h>
#include <hip/hip_bf16.h>

#define NN 100000   // nodes
#define H  256      // feature dim
#define NE 300000   // edges
#define KOUT 512    // y row length (u | v)

typedef __attribute__((ext_vector_type(8))) short short8;
typedef __attribute__((ext_vector_type(8))) unsigned short ushort8v;
typedef __attribute__((ext_vector_type(4))) float f32x4;

__device__ __forceinline__ unsigned short f2bf(float f) {
    unsigned int u = __float_as_uint(f);
    u += 0x7FFFu + ((u >> 16) & 1u);   // RNE
    return (unsigned short)(u >> 16);
}
__device__ __forceinline__ float bf2f(unsigned short h) {
    return __uint_as_float(((unsigned int)h) << 16);
}
// byte offset into a [rows][64] bf16 LDS tile (128B rows), XOR-swizzled
__device__ __forceinline__ int swz(int row, int coloff) {
    return row * 128 + (coloff ^ ((row & 7) << 4));
}

// ---------------- W-prep: W1 (fp32 [512][256]) -> 16 pre-swizzled bf16 tiles [128n][64k]
// tile t = nt*4+ks; element (n,kz) of tile stored at byte swz(n, kz*2).
// Wcat[k][j]: j<256 -> W1[k][j]; j>=256 -> W1[k+256][j-256];  j = nt*128+n, k = ks*64+kz.
__global__ __launch_bounds__(256) void wprep(const float* __restrict__ W1,
                                             unsigned short* __restrict__ wsB) {
    int gtid = blockIdx.x * 256 + threadIdx.x;   // 16384 threads
    int t  = gtid >> 10;
    int kg = (gtid >> 7) & 7;
    int n  = gtid & 127;
    int nt = t >> 2, ks = t & 3;
    int krow0 = ks * 64 + kg * 8 + ((nt >= 2) ? 256 : 0);
    int col = (nt & 1) * 128 + n;
    const float* src = W1 + (size_t)krow0 * 256 + col;
    ushort8v p;
    #pragma unroll
    for (int i = 0; i < 8; ++i) p[i] = f2bf(src[(size_t)i * 256]);
    *(ushort8v*)((char*)(wsB + t * 8192) + swz(n, kg * 16)) = p;
}

// ---------------- Phase 1 v2: y = x @ Wcat, 128x128 tile, BK=64, reg-prefetch pipeline
__global__ __launch_bounds__(256) void gemm_v2(const float* __restrict__ x,
                                               const unsigned short* __restrict__ wsB,
                                               unsigned short* __restrict__ y) {
    __shared__ unsigned short Al[128 * 64];
    __shared__ unsigned short Bl[128 * 64];
    const int tid = threadIdx.x;
    // bijective XCD swizzle: grid 3128 = 8 * 391; same-mt blocks co-XCD
    const int logical = ((int)blockIdx.x & 7) * ((int)gridDim.x >> 3) + ((int)blockIdx.x >> 3);
    const int mt = logical >> 2, nt = logical & 3;
    const int m0 = mt * 128;
    const int lane = tid & 63, wid = tid >> 6;
    const int wm = (wid >> 1) * 64, wn = (wid & 1) * 64;
    const int lr = lane & 15, lk = lane >> 4;

    const int arow = tid >> 2;          // 0..63
    const int acolb = (tid & 3) * 16;   // float col base within 64
    int r0 = m0 + arow;       if (r0 > NN - 1) r0 = NN - 1;
    int r1 = m0 + 64 + arow;  if (r1 > NN - 1) r1 = NN - 1;
    const float* xr0 = x + (size_t)r0 * H + acolb;
    const float* xr1 = x + (size_t)r1 * H + acolb;
    const unsigned short* bt = wsB + nt * 4 * 8192 + tid * 8;

    float4 pA[2][4];
    ushort8v pB[4];

    auto loadA = [&](int ks) {
        const float* s0 = xr0 + ks * 64;
        const float* s1 = xr1 + ks * 64;
        #pragma unroll
        for (int q = 0; q < 4; ++q) pA[0][q] = *(const float4*)(s0 + q * 4);
        #pragma unroll
        for (int q = 0; q < 4; ++q) pA[1][q] = *(const float4*)(s1 + q * 4);
    };
    auto loadB = [&](int ks) {
        const unsigned short* s = bt + ks * 8192;
        #pragma unroll
        for (int u = 0; u < 4; ++u) pB[u] = *(const ushort8v*)(s + u * 2048);
    };
    auto stage = [&]() {
        #pragma unroll
        for (int p = 0; p < 2; ++p) {
            int row = arow + p * 64;
            ushort8v q0, q1;
            q0[0]=f2bf(pA[p][0].x); q0[1]=f2bf(pA[p][0].y); q0[2]=f2bf(pA[p][0].z); q0[3]=f2bf(pA[p][0].w);
            q0[4]=f2bf(pA[p][1].x); q0[5]=f2bf(pA[p][1].y); q0[6]=f2bf(pA[p][1].z); q0[7]=f2bf(pA[p][1].w);
            q1[0]=f2bf(pA[p][2].x); q1[1]=f2bf(pA[p][2].y); q1[2]=f2bf(pA[p][2].z); q1[3]=f2bf(pA[p][2].w);
            q1[4]=f2bf(pA[p][3].x); q1[5]=f2bf(pA[p][3].y); q1[6]=f2bf(pA[p][3].z); q1[7]=f2bf(pA[p][3].w);
            *(ushort8v*)((char*)Al + swz(row, acolb * 2))      = q0;
            *(ushort8v*)((char*)Al + swz(row, acolb * 2 + 16)) = q1;
        }
        #pragma unroll
        for (int u = 0; u < 4; ++u) *(ushort8v*)(Bl + tid * 8 + u * 2048) = pB[u];
    };

    f32x4 acc[4][4] = {};
    loadA(0); loadB(0);
    #pragma unroll
    for (int ks = 0; ks < 4; ++ks) {
        stage();                       // converts + ds_writes (waits own loads)
        __syncthreads();               // tile ready for all waves
        if (ks < 3) { loadA(ks + 1); loadB(ks + 1); }   // prefetch flies under MFMA
        #pragma unroll
        for (int kk = 0; kk < 64; kk += 32) {
            short8 a[4], b[4];
            const int coloff = kk * 2 + lk * 16;
            #pragma unroll
            for (int mi = 0; mi < 4; ++mi)
                a[mi] = *(const short8*)((const char*)Al + swz(wm + mi * 16 + lr, coloff));
            #pragma unroll
            for (int ni = 0; ni < 4; ++ni)
                b[ni] = *(const short8*)((const char*)Bl + swz(wn + ni * 16 + lr, coloff));
            #pragma unroll
            for (int mi = 0; mi < 4; ++mi)
                #pragma unroll
                for (int ni = 0; ni < 4; ++ni)
                    acc[mi][ni] = __builtin_amdgcn_mfma_f32_16x16x32_bf16(a[mi], b[ni], acc[mi][ni], 0, 0, 0);
        }
        if (ks < 3) {
            // read-done barrier WITHOUT vmcnt drain: prefetch stays in flight
            asm volatile("s_waitcnt lgkmcnt(0)" ::: "memory");
            __builtin_amdgcn_s_barrier();
            __builtin_amdgcn_sched_barrier(0);
        }
    }
    // epilogue: D row=(lane>>4)*4+r, col=lane&15
    const int n0 = nt * 128;
    #pragma unroll
    for (int mi = 0; mi < 4; ++mi) {
        #pragma unroll
        for (int ni = 0; ni < 4; ++ni) {
            const int col = n0 + wn + ni * 16 + lr;
            #pragma unroll
            for (int r = 0; r < 4; ++r) {
                const int rowg = m0 + wm + mi * 16 + lk * 4 + r;
                if (rowg < NN) y[(size_t)rowg * KOUT + col] = f2bf(acc[mi][ni][r]);
            }
        }
    }
}

// ---------------- Phase 1 v1 (inline B staging) — fallback if ws lacks room for wsB
__global__ __launch_bounds__(256) void gemm_v1(const float* __restrict__ x,
                                               const float* __restrict__ W1,
                                               unsigned short* __restrict__ y) {
    __shared__ unsigned short Al[128 * 64];
    __shared__ unsigned short Bl[128 * 64];
    const int tid = threadIdx.x;
    const int bid = blockIdx.x;
    const int mt = bid >> 2, nt = bid & 3;
    const int m0 = mt * 128, n0 = nt * 128;
    const int lane = tid & 63, wid = tid >> 6;
    const int wm = (wid >> 1) * 64, wn = (wid & 1) * 64;
    const int lr = lane & 15, lk = lane >> 4;
    f32x4 acc[4][4] = {};
    for (int ks = 0; ks < 4; ++ks) {
        const int k0 = ks * 64;
        if (ks) __syncthreads();
        #pragma unroll
        for (int pass = 0; pass < 2; ++pass) {
            int f = pass * 4096 + tid * 16;
            int row = f >> 6, col = f & 63;
            int node = m0 + row;
            node = node < NN ? node : NN - 1;
            const float* src = x + (size_t)node * H + k0 + col;
            float4 v0 = *(const float4*)(src + 0);
            float4 v1 = *(const float4*)(src + 4);
            float4 v2 = *(const float4*)(src + 8);
            float4 v3 = *(const float4*)(src + 12);
            ushort8v p0, p1;
            p0[0]=f2bf(v0.x); p0[1]=f2bf(v0.y); p0[2]=f2bf(v0.z); p0[3]=f2bf(v0.w);
            p0[4]=f2bf(v1.x); p0[5]=f2bf(v1.y); p0[6]=f2bf(v1.z); p0[7]=f2bf(v1.w);
            p1[0]=f2bf(v2.x); p1[1]=f2bf(v2.y); p1[2]=f2bf(v2.z); p1[3]=f2bf(v2.w);
            p1[4]=f2bf(v3.x); p1[5]=f2bf(v3.y); p1[6]=f2bf(v3.z); p1[7]=f2bf(v3.w);
            *(ushort8v*)((char*)Al + swz(row, col * 2))      = p0;
            *(ushort8v*)((char*)Al + swz(row, col * 2 + 16)) = p1;
        }
        {
            int j  = tid & 127;
            int kh = tid >> 7;
            int rowbase = (n0 >= 256) ? 256 : 0;
            const float* wp = W1 + (size_t)(k0 + kh * 32 + rowbase) * 256 + (n0 & 255) + j;
            #pragma unroll
            for (int q = 0; q < 4; ++q) {
                ushort8v p;
                #pragma unroll
                for (int i = 0; i < 8; ++i) p[i] = f2bf(wp[(q * 8 + i) * 256]);
                *(ushort8v*)((char*)Bl + swz(j, (kh * 32 + q * 8) * 2)) = p;
            }
        }
        __syncthreads();
        #pragma unroll
        for (int kk = 0; kk < 64; kk += 32) {
            short8 a[4], b[4];
            const int coloff = kk * 2 + lk * 16;
            #pragma unroll
            for (int mi = 0; mi < 4; ++mi)
                a[mi] = *(const short8*)((const char*)Al + swz(wm + mi * 16 + lr, coloff));
            #pragma unroll
            for (int ni = 0; ni < 4; ++ni)
                b[ni] = *(const short8*)((const char*)Bl + swz(wn + ni * 16 + lr, coloff));
            #pragma unroll
            for (int mi = 0; mi < 4; ++mi)
                #pragma unroll
                for (int ni = 0; ni < 4; ++ni)
                    acc[mi][ni] = __builtin_amdgcn_mfma_f32_16x16x32_bf16(a[mi], b[ni], acc[mi][ni], 0, 0, 0);
        }
    }
    #pragma unroll
    for (int mi = 0; mi < 4; ++mi)
        #pragma unroll
        for (int ni = 0; ni < 4; ++ni) {
            const int col = n0 + wn + ni * 16 + lr;
            #pragma unroll
            for (int r = 0; r < 4; ++r) {
                const int rowg = m0 + wm + mi * 16 + lk * 4 + r;
                if (rowg < NN) y[(size_t)rowg * KOUT + col] = f2bf(acc[mi][ni][r]);
            }
        }
}

// ---------------- Phase 2 v2: half-wave per edge, ushort8 gathers
__global__ __launch_bounds__(256) void edge_v2(const unsigned short* __restrict__ y,
                                               const int* __restrict__ ei,
                                               const float* __restrict__ b1,
                                               const float* __restrict__ W2,
                                               const float* __restrict__ b2,
                                               float* __restrict__ out) {
    const int tid = threadIdx.x;
    const int l32 = tid & 31;
    const int ghw = ((int)(blockIdx.x * blockDim.x) + tid) >> 5;
    const int nhw = ((int)(gridDim.x * blockDim.x)) >> 5;
    const int j = l32 * 8;
    const float4 b01 = *(const float4*)(b1 + j);
    const float4 b23 = *(const float4*)(b1 + j + 4);
    const float4 w01 = *(const float4*)(W2 + j);
    const float4 w23 = *(const float4*)(W2 + j + 4);
    const float bb = b2[0];
    #pragma unroll 2
    for (int e = ghw; e < NE; e += nhw) {
        int s = ei[e], d = ei[NE + e];
        s = s < 0 ? 0 : (s > NN - 1 ? NN - 1 : s);
        d = d < 0 ? 0 : (d > NN - 1 ? NN - 1 : d);
        ushort8v us = *(const ushort8v*)(y + (size_t)s * KOUT + j);
        ushort8v ud = *(const ushort8v*)(y + (size_t)d * KOUT + 256 + j);
        float acc;
        acc  = fmaxf(bf2f(us[0]) + bf2f(ud[0]) + b01.x, 0.f) * w01.x;
        acc += fmaxf(bf2f(us[1]) + bf2f(ud[1]) + b01.y, 0.f) * w01.y;
        acc += fmaxf(bf2f(us[2]) + bf2f(ud[2]) + b01.z, 0.f) * w01.z;
        acc += fmaxf(bf2f(us[3]) + bf2f(ud[3]) + b01.w, 0.f) * w01.w;
        acc += fmaxf(bf2f(us[4]) + bf2f(ud[4]) + b23.x, 0.f) * w23.x;
        acc += fmaxf(bf2f(us[5]) + bf2f(ud[5]) + b23.y, 0.f) * w23.y;
        acc += fmaxf(bf2f(us[6]) + bf2f(ud[6]) + b23.z, 0.f) * w23.z;
        acc += fmaxf(bf2f(us[7]) + bf2f(ud[7]) + b23.w, 0.f) * w23.w;
        #pragma unroll
        for (int off = 16; off > 0; off >>= 1) acc += __shfl_xor(acc, off, 64);
        if (l32 == 0) out[e] = acc + bb;
    }
}

// ---------------- Fallback (ws too small): fused wave-per-edge, fp32. Slow but correct.
__global__ __launch_bounds__(256) void fused_fallback(const float* __restrict__ x,
                                                      const int* __restrict__ ei,
                                                      const float* __restrict__ W1,
                                                      const float* __restrict__ b1,
                                                      const float* __restrict__ W2,
                                                      const float* __restrict__ b2,
                                                      float* __restrict__ out) {
    __shared__ float xsh[4][512];
    const int lane = threadIdx.x & 63;
    const int wl = threadIdx.x >> 6;
    const int gw = (blockIdx.x * blockDim.x + threadIdx.x) >> 6;
    const int nw = (gridDim.x * blockDim.x) >> 6;
    const int j = lane * 4;
    const float4 bv = *(const float4*)(b1 + j);
    const float4 wv = *(const float4*)(W2 + j);
    const float bb = b2[0];
    for (int e = gw; e < NE; e += nw) {
        int s = ei[e], d = ei[NE + e];
        s = min(max(s, 0), NN - 1);
        d = min(max(d, 0), NN - 1);
        __threadfence_block();
        #pragma unroll
        for (int i = 0; i < 4; ++i) {
            xsh[wl][i * 64 + lane]       = x[(size_t)s * H + i * 64 + lane];
            xsh[wl][256 + i * 64 + lane] = x[(size_t)d * H + i * 64 + lane];
        }
        __threadfence_block();
        float h0 = bv.x, h1 = bv.y, h2 = bv.z, h3 = bv.w;
        for (int k = 0; k < 256; ++k) {
            float xa = xsh[wl][k], xb = xsh[wl][256 + k];
            float4 wa = *(const float4*)(W1 + (size_t)k * 256 + j);
            float4 wb = *(const float4*)(W1 + (size_t)(k + 256) * 256 + j);
            h0 += xa * wa.x + xb * wb.x;
            h1 += xa * wa.y + xb * wb.y;
            h2 += xa * wa.z + xb * wb.z;
            h3 += xa * wa.w + xb * wb.w;
        }
        float acc = fmaxf(h0, 0.f) * wv.x + fmaxf(h1, 0.f) * wv.y +
                    fmaxf(h2, 0.f) * wv.z + fmaxf(h3, 0.f) * wv.w;
        #pragma unroll
        for (int off = 32; off > 0; off >>= 1) acc += __shfl_xor(acc, off, 64);
        if (lane == 0) out[e] = acc + bb;
    }
}

extern "C" void kernel_launch(void* const* d_in, const int* in_sizes, int n_in,
                              void* d_out, int out_size, void* d_ws, size_t ws_size,
                              hipStream_t stream) {
    const float* x  = (const float*)d_in[0];
    const int*   ei = (const int*)d_in[1];
    const float* W1 = (const float*)d_in[2];
    const float* b1 = (const float*)d_in[3];
    const float* W2 = (const float*)d_in[4];
    const float* b2 = (const float*)d_in[5];
    float* out = (float*)d_out;

    const size_t ybytes = (size_t)NN * KOUT * sizeof(unsigned short);  // 102.4 MB
    const size_t wbytes = 16 * 8192 * sizeof(unsigned short);          // 256 KB
    const int mtiles = (NN + 127) / 128;  // 782

    if (ws_size >= ybytes + wbytes) {
        unsigned short* yb = (unsigned short*)d_ws;
        unsigned short* wb = (unsigned short*)((char*)d_ws + ybytes);
        wprep<<<dim3(64), dim3(256), 0, stream>>>(W1, wb);
        gemm_v2<<<dim3(mtiles * 4), dim3(256), 0, stream>>>(x, wb, yb);
        edge_v2<<<dim3(2048), dim3(256), 0, stream>>>(yb, ei, b1, W2, b2, out);
    } else if (ws_size >= ybytes) {
        unsigned short* yb = (unsigned short*)d_ws;
        gemm_v1<<<dim3(mtiles * 4), dim3(256), 0, stream>>>(x, W1, yb);
        edge_v2<<<dim3(2048), dim3(256), 0, stream>>>(yb, ei, b1, W2, b2, out);
    } else {
        fused_fallback<<<dim3(2048), dim3(256), 0, stream>>>(x, ei, W1, b1, W2, b2, out);
    }
}